// Round 1
// baseline (1403.778 us; speedup 1.0000x reference)
//
#include <hip/hip_runtime.h>
#include <hip/hip_bf16.h>
#include <math.h>

typedef unsigned short ushort_t;
typedef __bf16 bf16x8 __attribute__((ext_vector_type(8)));
typedef float f32x4 __attribute__((ext_vector_type(4)));

#define BB 128
#define TT 24
#define EE 512
#define VV 30000
#define HH 1024
#define GG 4096
#define MM (BB*TT)   // 3072 rows, m = t*128 + b

static __device__ __forceinline__ ushort_t f2bf(float x) {
  __hip_bfloat16 h = __float2bfloat16(x);
  return __builtin_bit_cast(ushort_t, h);
}

// ---------------- prep kernels ----------------

__global__ void cast_bf16_k(const float* __restrict__ s, ushort_t* __restrict__ d, int n4) {
  int i = blockIdx.x * blockDim.x + threadIdx.x;
  int stride = gridDim.x * blockDim.x;
  for (; i < n4; i += stride) {
    float4 v = reinterpret_cast<const float4*>(s)[i];
    ushort4 o;
    o.x = f2bf(v.x); o.y = f2bf(v.y); o.z = f2bf(v.z); o.w = f2bf(v.w);
    reinterpret_cast<ushort4*>(d)[i] = o;
  }
}

__global__ void bias_sum_k(const float* __restrict__ bi, const float* __restrict__ bh,
                           float* __restrict__ bs) {
  int i = blockIdx.x * blockDim.x + threadIdx.x;
  if (i < GG) bs[i] = bi[i] + bh[i];
}

// xa[(t*128+b)][0:512] = emb[cap], [512:1024] = features[b]; cap = t==0 ? pad : captions[b][t-1]
__global__ void build_xa_k(const float* __restrict__ emb, const int* __restrict__ captions,
                           const int* __restrict__ pad_idx, const float* __restrict__ features,
                           ushort_t* __restrict__ xa) {
  int row = blockIdx.x;          // 0..3071
  int t = row >> 7;
  int b = row & 127;
  int cap = (t == 0) ? pad_idx[0] : captions[b * TT + (t - 1)];
  const float* s0 = emb + (size_t)cap * EE;
  const float* s1 = features + (size_t)b * EE;
  ushort_t* d = xa + (size_t)row * (2 * EE);
  for (int e = threadIdx.x; e < EE; e += 256) {
    d[e] = f2bf(s0[e]);
    d[EE + e] = f2bf(s1[e]);
  }
}

__global__ void init_state_k(ushort_t* __restrict__ h0, float* __restrict__ c) {
  int i = blockIdx.x * blockDim.x + threadIdx.x;
  if (i < BB * HH) { h0[i] = 0; c[i] = 0.f; }
}

// ---------------- GEMM (both operands [rows][K=1024] bf16) ----------------
// out[m][n] = dot(A[m], B[n])   (D-frag: m = (lane>>4)*4+reg, n = lane&15)
// MODE 0: xg — out[m*N + n] + bias[n]
// MODE 1: logits — m = v (guard < M), n = b*24+t; out[b*V*T + v*T + t] + bias[v]
template<int MODE>
__global__ __launch_bounds__(256) void gemm_bt(
    const ushort_t* __restrict__ A,
    const ushort_t* __restrict__ Bm,
    const float* __restrict__ bias,
    float* __restrict__ out,
    int M, int N)
{
  constexpr int K = 1024;
  __shared__ __align__(16) ushort_t As[128][72];
  __shared__ __align__(16) ushort_t Bs[128][72];
  const int m0 = blockIdx.y * 128, n0 = blockIdx.x * 128;
  const int tid = threadIdx.x;
  const int wid = tid >> 6, lane = tid & 63;
  const int wm = (wid >> 1) * 64, wn = (wid & 1) * 64;
  const int lr = tid >> 3, lc = (tid & 7) * 8;
  f32x4 acc[4][4] = {};
  for (int k0 = 0; k0 < K; k0 += 64) {
    #pragma unroll
    for (int p = 0; p < 4; ++p) {
      int row = lr + p * 32;
      int gr = m0 + row;
      uint4 v = {0u, 0u, 0u, 0u};
      if (gr < M)
        v = *reinterpret_cast<const uint4*>(A + (size_t)gr * K + k0 + lc);
      *reinterpret_cast<uint4*>(&As[row][lc]) = v;
      uint4 wv = *reinterpret_cast<const uint4*>(Bm + (size_t)(n0 + row) * K + k0 + lc);
      *reinterpret_cast<uint4*>(&Bs[row][lc]) = wv;
    }
    __syncthreads();
    const int rr = lane & 15, kb = (lane >> 4) * 8;
    #pragma unroll
    for (int kk = 0; kk < 2; ++kk) {
      const int kof = kk * 32 + kb;
      bf16x8 af[4], bfv[4];
      #pragma unroll
      for (int i = 0; i < 4; ++i)
        af[i] = *reinterpret_cast<const bf16x8*>(&As[wm + i * 16 + rr][kof]);
      #pragma unroll
      for (int j = 0; j < 4; ++j)
        bfv[j] = *reinterpret_cast<const bf16x8*>(&Bs[wn + j * 16 + rr][kof]);
      #pragma unroll
      for (int i = 0; i < 4; ++i)
        #pragma unroll
        for (int j = 0; j < 4; ++j)
          acc[i][j] = __builtin_amdgcn_mfma_f32_16x16x32_bf16(af[i], bfv[j], acc[i][j], 0, 0, 0);
    }
    __syncthreads();
  }
  const int l16 = lane & 15, l4 = lane >> 4;
  if (MODE == 0) {
    #pragma unroll
    for (int i = 0; i < 4; ++i) {
      #pragma unroll
      for (int j = 0; j < 4; ++j) {
        int n = n0 + wn + j * 16 + l16;
        float bv = bias[n];
        #pragma unroll
        for (int r = 0; r < 4; ++r) {
          int m = m0 + wm + i * 16 + l4 * 4 + r;
          out[(size_t)m * N + n] = acc[i][j][r] + bv;
        }
      }
    }
  } else {
    #pragma unroll
    for (int i = 0; i < 4; ++i) {
      #pragma unroll
      for (int r = 0; r < 4; ++r) {
        int v = m0 + wm + i * 16 + l4 * 4 + r;
        if (v < M) {
          float bv = bias[v];
          #pragma unroll
          for (int j = 0; j < 4; ++j) {
            int n = n0 + wn + j * 16 + l16;
            int bb = n / TT, tq = n - bb * TT;
            out[(size_t)bb * ((size_t)VV * TT) + (size_t)v * TT + tq] = acc[i][j][r] + bv;
          }
        }
      }
    }
  }
}

// ---------------- fused LSTM step ----------------
// Block handles j-range [j0, j0+16) for ALL 4 gates (permuted B-rows), all 128 batch rows.
// Wave w: batch rows [w*32, w*32+32), n = gate*16 + j within tile.
// acc[i][gate][r] with (b = w*32 + i*16 + (lane>>4)*4 + r, j = j0 + (lane&15)).
__global__ __launch_bounds__(256) void lstm_step_k(
    const ushort_t* __restrict__ h_in,   // [128][1024] bf16
    const ushort_t* __restrict__ Whh,    // [4096][1024] bf16
    const float* __restrict__ xg,        // [3072][4096] f32 (bias included)
    float* __restrict__ c,               // [128][1024] f32
    ushort_t* __restrict__ h_out,        // [128][1024] bf16
    ushort_t* __restrict__ hs,           // [3072][1024] bf16, row = b*24 + t
    int t)
{
  __shared__ __align__(16) ushort_t As[128][72];
  __shared__ __align__(16) ushort_t Bs[64][72];
  const int j0 = blockIdx.x * 16;
  const int tid = threadIdx.x;
  const int wid = tid >> 6, lane = tid & 63;
  const int wm = wid * 32;
  const int lr = tid >> 3, lc = (tid & 7) * 8;
  f32x4 acc[2][4] = {};
  for (int k0 = 0; k0 < 1024; k0 += 64) {
    #pragma unroll
    for (int p = 0; p < 4; ++p) {
      int row = lr + p * 32;
      *reinterpret_cast<uint4*>(&As[row][lc]) =
          *reinterpret_cast<const uint4*>(h_in + (size_t)row * 1024 + k0 + lc);
    }
    #pragma unroll
    for (int p = 0; p < 2; ++p) {
      int row = lr + p * 32;                        // 0..63
      int brow = (row >> 4) * 1024 + j0 + (row & 15);
      *reinterpret_cast<uint4*>(&Bs[row][lc]) =
          *reinterpret_cast<const uint4*>(Whh + (size_t)brow * 1024 + k0 + lc);
    }
    __syncthreads();
    const int rr = lane & 15, kb = (lane >> 4) * 8;
    #pragma unroll
    for (int kk = 0; kk < 2; ++kk) {
      const int kof = kk * 32 + kb;
      bf16x8 af[2], bfv[4];
      af[0] = *reinterpret_cast<const bf16x8*>(&As[wm + rr][kof]);
      af[1] = *reinterpret_cast<const bf16x8*>(&As[wm + 16 + rr][kof]);
      #pragma unroll
      for (int j = 0; j < 4; ++j)
        bfv[j] = *reinterpret_cast<const bf16x8*>(&Bs[j * 16 + rr][kof]);
      #pragma unroll
      for (int i = 0; i < 2; ++i)
        #pragma unroll
        for (int j = 0; j < 4; ++j)
          acc[i][j] = __builtin_amdgcn_mfma_f32_16x16x32_bf16(af[i], bfv[j], acc[i][j], 0, 0, 0);
    }
    __syncthreads();
  }
  const int l16 = lane & 15, l4 = lane >> 4;
  const int jg = j0 + l16;
  #pragma unroll
  for (int i = 0; i < 2; ++i) {
    #pragma unroll
    for (int r = 0; r < 4; ++r) {
      int b = wm + i * 16 + l4 * 4 + r;
      size_t xb = ((size_t)(t * 128 + b)) * 4096;
      float gi = acc[i][0][r] + xg[xb + jg];
      float gf = acc[i][1][r] + xg[xb + 1024 + jg];
      float gg = acc[i][2][r] + xg[xb + 2048 + jg];
      float go = acc[i][3][r] + xg[xb + 3072 + jg];
      gi = 1.f / (1.f + expf(-gi));
      gf = 1.f / (1.f + expf(-gf));
      go = 1.f / (1.f + expf(-go));
      float cn = gf * c[b * 1024 + jg] + gi * tanhf(gg);
      float hn = go * tanhf(cn);
      c[b * 1024 + jg] = cn;
      ushort_t hb = f2bf(hn);
      h_out[b * 1024 + jg] = hb;
      hs[((size_t)b * TT + t) * 1024 + jg] = hb;
    }
  }
}

// ---------------- launcher ----------------

extern "C" void kernel_launch(void* const* d_in, const int* in_sizes, int n_in,
                              void* d_out, int out_size, void* d_ws, size_t ws_size,
                              hipStream_t stream) {
  const float* features = (const float*)d_in[0];
  const int*   captions = (const int*)d_in[1];
  const int*   pad_idx  = (const int*)d_in[2];
  const float* emb      = (const float*)d_in[3];
  const float* W_ih     = (const float*)d_in[4];
  const float* W_hh     = (const float*)d_in[5];
  const float* b_ih     = (const float*)d_in[6];
  const float* b_hh     = (const float*)d_in[7];
  const float* W_out    = (const float*)d_in[8];
  const float* b_out    = (const float*)d_in[9];
  float* out = (float*)d_out;

  char* w = (char*)d_ws;
  auto carve = [&](size_t bytes) {
    char* p = w;
    w += (bytes + 255) & ~(size_t)255;
    return p;
  };
  ushort_t* Wih_b  = (ushort_t*)carve((size_t)GG * HH * 2);
  ushort_t* Whh_b  = (ushort_t*)carve((size_t)GG * HH * 2);
  ushort_t* Wout_b = (ushort_t*)carve((size_t)VV * HH * 2);
  ushort_t* xa     = (ushort_t*)carve((size_t)MM * HH * 2);
  float*    xg     = (float*)carve((size_t)MM * GG * 4);
  ushort_t* hs     = (ushort_t*)carve((size_t)MM * HH * 2);
  ushort_t* h0     = (ushort_t*)carve((size_t)BB * HH * 2);
  ushort_t* h1     = (ushort_t*)carve((size_t)BB * HH * 2);
  float*    cbuf   = (float*)carve((size_t)BB * HH * 4);
  float*    bsum   = (float*)carve((size_t)GG * 4);

  cast_bf16_k<<<dim3(1024), 256, 0, stream>>>(W_ih, Wih_b, GG * HH / 4);
  cast_bf16_k<<<dim3(1024), 256, 0, stream>>>(W_hh, Whh_b, GG * HH / 4);
  cast_bf16_k<<<dim3(2048), 256, 0, stream>>>(W_out, Wout_b, VV * HH / 4);
  bias_sum_k<<<dim3(16), 256, 0, stream>>>(b_ih, b_hh, bsum);
  build_xa_k<<<dim3(MM), 256, 0, stream>>>(emb, captions, pad_idx, features, xa);
  init_state_k<<<dim3(512), 256, 0, stream>>>(h0, cbuf);

  // xg = xa @ W_ih^T + (b_ih + b_hh)   [3072 x 4096]
  gemm_bt<0><<<dim3(GG / 128, MM / 128), 256, 0, stream>>>(xa, Wih_b, bsum, xg, MM, GG);

  // 24 sequential LSTM steps
  for (int t = 0; t < TT; ++t) {
    ushort_t* hin  = (t & 1) ? h1 : h0;
    ushort_t* hout = (t & 1) ? h0 : h1;
    lstm_step_k<<<dim3(64), 256, 0, stream>>>(hin, Whh_b, xg, cbuf, hout, hs, t);
  }

  // out[b][v][t] = dot(hs[b*24+t], W_out[v]) + b_out[v]
  gemm_bt<1><<<dim3(MM / 128, (VV + 127) / 128), 256, 0, stream>>>(Wout_b, hs, b_out, out, VV, MM);
}

// Round 2
// 921.494 us; speedup vs baseline: 1.5234x; 1.5234x over previous
//
#include <hip/hip_runtime.h>
#include <hip/hip_bf16.h>
#include <math.h>

typedef unsigned short ushort_t;
typedef __bf16 bf16x8 __attribute__((ext_vector_type(8)));
typedef float f32x4 __attribute__((ext_vector_type(4)));

#define BB 128
#define TT 24
#define EE 512
#define VV 30000
#define HH 1024
#define GG 4096
#define MM (BB*TT)   // 3072 rows, m = t*128 + b

static __device__ __forceinline__ ushort_t f2bf(float x) {
  __hip_bfloat16 h = __float2bfloat16(x);
  return __builtin_bit_cast(ushort_t, h);
}

// async global->LDS, 16B per lane; lds base must be wave-uniform
static __device__ __forceinline__ void gld_lds16(const void* g, void* l) {
  __builtin_amdgcn_global_load_lds((const __attribute__((address_space(1))) void*)g,
                                   (__attribute__((address_space(3))) void*)l, 16, 0, 0);
}

// ---------------- prep kernels ----------------

__global__ void cast_bf16_k(const float* __restrict__ s, ushort_t* __restrict__ d, int n4) {
  int i = blockIdx.x * blockDim.x + threadIdx.x;
  int stride = gridDim.x * blockDim.x;
  for (; i < n4; i += stride) {
    float4 v = reinterpret_cast<const float4*>(s)[i];
    ushort4 o;
    o.x = f2bf(v.x); o.y = f2bf(v.y); o.z = f2bf(v.z); o.w = f2bf(v.w);
    reinterpret_cast<ushort4*>(d)[i] = o;
  }
}

__global__ void bias_sum_k(const float* __restrict__ bi, const float* __restrict__ bh,
                           float* __restrict__ bs) {
  int i = blockIdx.x * blockDim.x + threadIdx.x;
  if (i < GG) bs[i] = bi[i] + bh[i];
}

__global__ void build_xa_k(const float* __restrict__ emb, const int* __restrict__ captions,
                           const int* __restrict__ pad_idx, const float* __restrict__ features,
                           ushort_t* __restrict__ xa) {
  int row = blockIdx.x;          // 0..3071, row = t*128+b
  int t = row >> 7;
  int b = row & 127;
  int cap = (t == 0) ? pad_idx[0] : captions[b * TT + (t - 1)];
  const float* s0 = emb + (size_t)cap * EE;
  const float* s1 = features + (size_t)b * EE;
  ushort_t* d = xa + (size_t)row * (2 * EE);
  for (int e = threadIdx.x; e < EE; e += 256) {
    d[e] = f2bf(s0[e]);
    d[EE + e] = f2bf(s1[e]);
  }
}

__global__ void zero_bar_k(int* __restrict__ bar) {
  if (threadIdx.x < 2) bar[threadIdx.x] = 0;
}

// ---------------- GEMM, m97 structure ----------------
// A,B: [rows][K=1024] bf16. out[m][n] = dot(A[m],B[n]).
// MODE 0: out[m*N+n] + bias[n].  MODE 1: m=v (guard<M), n=b*24+t -> out[b*V*T + v*T + t] + bias[v]
template<int MODE>
__global__ __launch_bounds__(256) void gemm_bt(
    const ushort_t* __restrict__ A,
    const ushort_t* __restrict__ Bm,
    const float* __restrict__ bias,
    float* __restrict__ out,
    int M, int N, int nx, int cpx)
{
  constexpr int K = 1024;
  __shared__ __align__(16) ushort_t As[128 * 64];
  __shared__ __align__(16) ushort_t Bs[128 * 64];
  int bid = blockIdx.x;
  int bid_s = (bid & 7) * cpx + (bid >> 3);       // XCD-contiguous chunks
  const int n0 = (bid_s % nx) * 128;
  const int m0 = (bid_s / nx) * 128;
  const int tid = threadIdx.x;
  const int wid = tid >> 6, lane = tid & 63;
  const int wm = (wid >> 1) * 64, wn = (wid & 1) * 64;
  const int srow = lane >> 3;            // 0..7
  const int scol = (lane & 7) * 8;       // element offset
  const int rr = lane & 15, kb = (lane >> 4) * 8;
  f32x4 acc[4][4] = {};
  for (int k0 = 0; k0 < K; k0 += 64) {
    #pragma unroll
    for (int p = 0; p < 4; ++p) {
      int c = p * 4 + wid;               // chunk 0..15, 8 rows each
      int row = c * 8 + srow;
      gld_lds16(A + (size_t)(m0 + row) * K + k0 + scol, As + c * 512);
      gld_lds16(Bm + (size_t)(n0 + row) * K + k0 + scol, Bs + c * 512);
    }
    __syncthreads();
    #pragma unroll
    for (int kk = 0; kk < 2; ++kk) {
      const int kof = kk * 32 + kb;
      bf16x8 af[4], bfv[4];
      #pragma unroll
      for (int i = 0; i < 4; ++i)
        af[i] = *reinterpret_cast<const bf16x8*>(As + (wm + i * 16 + rr) * 64 + kof);
      #pragma unroll
      for (int j = 0; j < 4; ++j)
        bfv[j] = *reinterpret_cast<const bf16x8*>(Bs + (wn + j * 16 + rr) * 64 + kof);
      #pragma unroll
      for (int i = 0; i < 4; ++i)
        #pragma unroll
        for (int j = 0; j < 4; ++j)
          acc[i][j] = __builtin_amdgcn_mfma_f32_16x16x32_bf16(af[i], bfv[j], acc[i][j], 0, 0, 0);
    }
    __syncthreads();
  }
  const int l16 = lane & 15, l4 = lane >> 4;
  if (MODE == 0) {
    #pragma unroll
    for (int i = 0; i < 4; ++i) {
      #pragma unroll
      for (int j = 0; j < 4; ++j) {
        int n = n0 + wn + j * 16 + l16;
        float bv = bias[n];
        #pragma unroll
        for (int r = 0; r < 4; ++r) {
          int m = m0 + wm + i * 16 + l4 * 4 + r;
          out[(size_t)m * N + n] = acc[i][j][r] + bv;
        }
      }
    }
  } else {
    #pragma unroll
    for (int i = 0; i < 4; ++i) {
      #pragma unroll
      for (int r = 0; r < 4; ++r) {
        int v = m0 + wm + i * 16 + l4 * 4 + r;
        if (v < M) {
          float bv = bias[v];
          #pragma unroll
          for (int j = 0; j < 4; ++j) {
            int n = n0 + wn + j * 16 + l16;
            int bb = n / TT, tq = n - bb * TT;
            out[(size_t)bb * ((size_t)VV * TT) + (size_t)v * TT + tq] = acc[i][j][r] + bv;
          }
        }
      }
    }
  }
}

// ---------------- fused persistent LSTM (all 24 steps, grid barrier) ----------------
// 128 blocks: jblk = bid&63 (16 j-cols x 4 gates), mblk = bid>>6 (64 batch rows).
// Whh tile resident in LDS; c in registers; h ping-pong via global + grid barrier.
__global__ __launch_bounds__(256, 1) void lstm_seq_k(
    const ushort_t* __restrict__ Whh,    // [4096][1024] bf16
    const float* __restrict__ xg,        // [3072][4096] f32, row = t*128+b, bias included
    ushort_t* __restrict__ hb0,
    ushort_t* __restrict__ hb1,          // [128][1024] bf16 ping-pong
    ushort_t* __restrict__ hs,           // [3072][1024] bf16, row = b*24+t
    int* __restrict__ bar)               // bar[0]=cnt, bar[1]=release
{
  __shared__ __align__(16) ushort_t Wt[64 * 1032];   // 64 rows x (1024+8 pad)
  __shared__ __align__(16) ushort_t Ast[2][64 * 64];
  const int tid = threadIdx.x, wid = tid >> 6, lane = tid & 63;
  const int jblk = blockIdx.x & 63, mblk = blockIdx.x >> 6;
  const int j0 = jblk * 16, m0 = mblk * 64;
  // one-time Whh tile load: LDS row n (= g*16+jj) <- Whh row g*1024 + j0 + jj
  for (int idx = tid; idx < 64 * 128; idx += 256) {
    int r = idx >> 7, c16 = idx & 127;
    int grow = ((r >> 4) << 10) + j0 + (r & 15);
    *reinterpret_cast<uint4*>(&Wt[r * 1032 + c16 * 8]) =
        *reinterpret_cast<const uint4*>(Whh + (size_t)grow * 1024 + c16 * 8);
  }
  __syncthreads();
  const int rr = lane & 15, kb = (lane >> 4) * 8, l4 = lane >> 4;
  const int jg = j0 + rr;
  const int srow = lane >> 3, scol = (lane & 7) * 8;
  float c_reg[4] = {0.f, 0.f, 0.f, 0.f};
  for (int t = 0; t < TT; ++t) {
    const ushort_t* hin = (t & 1) ? hb1 : hb0;
    ushort_t* hout = (t & 1) ? hb0 : hb1;
    f32x4 acc[4] = {};
    if (t > 0) {
      // prologue: stage chunk 0 into buf 0
      #pragma unroll
      for (int p = 0; p < 2; ++p) {
        int c = p * 4 + wid;
        gld_lds16(hin + (size_t)(m0 + c * 8 + srow) * HH + 0 + scol, Ast[0] + c * 512);
      }
      for (int kc = 0; kc < 16; ++kc) {
        if (kc < 15) {
          const int kn = (kc + 1) * 64;
          #pragma unroll
          for (int p = 0; p < 2; ++p) {
            int c = p * 4 + wid;
            gld_lds16(hin + (size_t)(m0 + c * 8 + srow) * HH + kn + scol,
                      Ast[(kc + 1) & 1] + c * 512);
          }
          asm volatile("s_waitcnt vmcnt(2)" ::: "memory");
        } else {
          asm volatile("s_waitcnt vmcnt(0)" ::: "memory");
        }
        __builtin_amdgcn_s_barrier();
        const ushort_t* Ab = Ast[kc & 1];
        const int k0 = kc * 64;
        #pragma unroll
        for (int kk = 0; kk < 2; ++kk) {
          const int kof = kk * 32 + kb;
          bf16x8 af = *reinterpret_cast<const bf16x8*>(Ab + (wid * 16 + rr) * 64 + kof);
          #pragma unroll
          for (int g = 0; g < 4; ++g) {
            bf16x8 bv = *reinterpret_cast<const bf16x8*>(Wt + (g * 16 + rr) * 1032 + k0 + kof);
            acc[g] = __builtin_amdgcn_mfma_f32_16x16x32_bf16(af, bv, acc[g], 0, 0, 0);
          }
        }
        asm volatile("" ::: "memory");
        __builtin_amdgcn_s_barrier();
        asm volatile("" ::: "memory");
      }
    }
    // elementwise LSTM update; wave wid owns batch rows [m0+wid*16, +16)
    #pragma unroll
    for (int r = 0; r < 4; ++r) {
      int b = m0 + wid * 16 + l4 * 4 + r;
      size_t xb = ((size_t)(t * BB + b)) * GG;
      float gi = acc[0][r] + xg[xb + jg];
      float gf = acc[1][r] + xg[xb + 1024 + jg];
      float gg = acc[2][r] + xg[xb + 2048 + jg];
      float go = acc[3][r] + xg[xb + 3072 + jg];
      gi = 1.f / (1.f + expf(-gi));
      gf = 1.f / (1.f + expf(-gf));
      go = 1.f / (1.f + expf(-go));
      float cn = gf * c_reg[r] + gi * tanhf(gg);
      c_reg[r] = cn;
      float hn = go * tanhf(cn);
      ushort_t hb = f2bf(hn);
      hout[(size_t)b * HH + jg] = hb;
      hs[((size_t)b * TT + t) * HH + jg] = hb;
    }
    // grid barrier between steps (generation-based, monotone counter)
    if (t < TT - 1) {
      __syncthreads();
      if (tid == 0) {
        __threadfence();
        int a = atomicAdd(bar, 1) + 1;
        if (a == 128 * (t + 1)) {
          __hip_atomic_store(bar + 1, t + 1, __ATOMIC_RELEASE, __HIP_MEMORY_SCOPE_AGENT);
        } else {
          while (__hip_atomic_load(bar + 1, __ATOMIC_ACQUIRE, __HIP_MEMORY_SCOPE_AGENT) < t + 1)
            __builtin_amdgcn_s_sleep(2);
        }
        __threadfence();
      }
      __syncthreads();
    }
  }
}

// ---------------- launcher ----------------

extern "C" void kernel_launch(void* const* d_in, const int* in_sizes, int n_in,
                              void* d_out, int out_size, void* d_ws, size_t ws_size,
                              hipStream_t stream) {
  const float* features = (const float*)d_in[0];
  const int*   captions = (const int*)d_in[1];
  const int*   pad_idx  = (const int*)d_in[2];
  const float* emb      = (const float*)d_in[3];
  const float* W_ih     = (const float*)d_in[4];
  const float* W_hh     = (const float*)d_in[5];
  const float* b_ih     = (const float*)d_in[6];
  const float* b_hh     = (const float*)d_in[7];
  const float* W_out    = (const float*)d_in[8];
  const float* b_out    = (const float*)d_in[9];
  float* out = (float*)d_out;

  char* w = (char*)d_ws;
  auto carve = [&](size_t bytes) {
    char* p = w;
    w += (bytes + 255) & ~(size_t)255;
    return p;
  };
  ushort_t* Wih_b  = (ushort_t*)carve((size_t)GG * HH * 2);
  ushort_t* Whh_b  = (ushort_t*)carve((size_t)GG * HH * 2);
  ushort_t* Wout_b = (ushort_t*)carve((size_t)30080 * HH * 2);  // padded to tile multiple
  ushort_t* xa     = (ushort_t*)carve((size_t)MM * HH * 2);
  float*    xg     = (float*)carve((size_t)MM * GG * 4);
  ushort_t* hs     = (ushort_t*)carve((size_t)MM * HH * 2);
  ushort_t* h0     = (ushort_t*)carve((size_t)BB * HH * 2);
  ushort_t* h1     = (ushort_t*)carve((size_t)BB * HH * 2);
  float*    bsum   = (float*)carve((size_t)GG * 4);
  int*      bar    = (int*)carve(256);

  cast_bf16_k<<<dim3(1024), 256, 0, stream>>>(W_ih, Wih_b, GG * HH / 4);
  cast_bf16_k<<<dim3(1024), 256, 0, stream>>>(W_hh, Whh_b, GG * HH / 4);
  cast_bf16_k<<<dim3(2048), 256, 0, stream>>>(W_out, Wout_b, VV * HH / 4);
  bias_sum_k<<<dim3(16), 256, 0, stream>>>(b_ih, b_hh, bsum);
  build_xa_k<<<dim3(MM), 256, 0, stream>>>(emb, captions, pad_idx, features, xa);
  zero_bar_k<<<dim3(1), 64, 0, stream>>>(bar);

  // xg = xa @ W_ih^T + (b_ih+b_hh)  [3072 x 4096]; grid 32x24=768 = 8*96
  gemm_bt<0><<<dim3(768), 256, 0, stream>>>(xa, Wih_b, bsum, xg, MM, GG, 32, 96);

  // all 24 LSTM steps in one persistent kernel
  lstm_seq_k<<<dim3(128), 256, 0, stream>>>(Whh_b, xg, h0, h1, hs, bar);

  // out[b][v][t] = dot(hs[b*24+t], W_out[v]) + b_out[v]; grid 24x235=5640 = 8*705
  gemm_bt<1><<<dim3(5640), 256, 0, stream>>>(Wout_b, hs, b_out, out, VV, MM, 24, 705);
}